// Round 14
// baseline (48.284 us; speedup 1.0000x reference)
//
#include <hip/hip_runtime.h>
#include <hip/hip_bf16.h>
#include <math.h>

typedef __attribute__((ext_vector_type(8))) __bf16 bf16x8;
typedef __attribute__((ext_vector_type(4))) float f32x4;

constexpr float VX_ = 0.2f;
constexpr float VY_ = 0.2f;
constexpr float X_OFF_ = 0.1f;    // VX/2 + 0.0
constexpr float Y_OFF_ = -39.9f;  // VY/2 - 40.0
constexpr float EPS_ = 1e-3f;

__device__ __forceinline__ float wave_sum(float v) {
#pragma unroll
  for (int off = 32; off; off >>= 1) v += __shfl_xor(v, off);
  return v;
}

__device__ __forceinline__ ushort bf16bits(float x) {
  __hip_bfloat16 h = __float2bfloat16(x);
  return __builtin_bit_cast(ushort, h);
}

// packed RNE f32x2 -> bf16x2 (gfx950 has the instruction but no builtin)
__device__ __forceinline__ uint32_t cvtpk(float lo, float hi) {
  uint32_t r;
  asm("v_cvt_pk_bf16_f32 %0, %1, %2" : "=v"(r) : "v"(lo), "v"(hi));
  return r;
}

// k0 (one block): compute G' (scaled W^T W, off-diag doubled) + wsum and
// pre-pack the MFMA B fragments, so k1/k4 never rebuild them per block.
__global__ __launch_bounds__(256) void k0_prep(const float* __restrict__ W,
                                               float* __restrict__ gws,
                                               uint32_t* __restrict__ Bpack) {
  const int t = threadIdx.x;
  if (t < 180) {  // G': 45 pairs x 4-way split over o
    const int pr = t >> 2, k = t & 3;
    int c = 0, rem = pr;
    while (rem >= 9 - c) {
      rem -= 9 - c;
      ++c;
    }
    const int c2 = c + rem;
    float s = 0.f;
    for (int o = k * 16; o < k * 16 + 16; ++o) s += W[o * 9 + c] * W[o * 9 + c2];
    s += __shfl_xor(s, 1);
    s += __shfl_xor(s, 2);
    if (k == 0) gws[pr] = (c == c2) ? s : 2.f * s;
  } else if (t < 216) {  // wsum: 9 cols x 4-way split
    const int tt = t - 180, c = tt >> 2, k = tt & 3;
    float s = 0.f;
    for (int o = k * 16; o < k * 16 + 16; ++o) s += W[o * 9 + c];
    s += __shfl_xor(s, 1);
    s += __shfl_xor(s, 2);
    if (k == 0) gws[45 + c] = s;
  }
  {  // Bpack[t]: 8 bf16 = B fragment for (nt = t>>6, lane = t&63)
    const int nt = t >> 6, lane = t & 63;
    const int l16 = lane & 15, g16 = lane >> 4;
    const int col = nt * 16 + l16;
    ushort h[8];
#pragma unroll
    for (int j = 0; j < 8; ++j) {
      const int kk = 8 * g16 + j;
      h[j] = (kk < 9) ? bf16bits(W[col * 9 + kk]) : (ushort)0;
    }
    uint4 q;
    q.x = (uint)h[0] | ((uint)h[1] << 16);
    q.y = (uint)h[2] | ((uint)h[3] << 16);
    q.z = (uint)h[4] | ((uint)h[5] << 16);
    q.w = (uint)h[6] | ((uint)h[7] << 16);
    *reinterpret_cast<uint4*>(Bpack + (size_t)t * 4) = q;
  }
}

// k1: per-n sums of x and x^2, pre-contracted with G'/wsum (2-float
// accumulator per thread). ALSO stores per-pillar aux {m0,m1,m2,ox,oy,np}
// so k4 needs no wave_sum / npts / coors at all. partials layout:
// [(n*2 + j) * S + block].
__global__ __launch_bounds__(256) void k1_moments(
    const float* __restrict__ feats, const int* __restrict__ npts_arr,
    const int* __restrict__ coors, const float* __restrict__ gwsbuf,
    float* __restrict__ partials, float* __restrict__ aux, int S, int P) {
  __shared__ float2 red[4][64];
  const int t = threadIdx.x, lane = t & 63, wv = t >> 6;
  float g[45], wsv[9];
#pragma unroll
  for (int i = 0; i < 45; ++i) g[i] = gwsbuf[i];  // uniform -> scalar loads
#pragma unroll
  for (int i = 0; i < 9; ++i) wsv[i] = gwsbuf[45 + i];

  float s1 = 0.f, s2 = 0.f;
  const int nw = S * 4;
  int p = blockIdx.x * 4 + wv;
  if (p < P) {
    float4 f =
        *reinterpret_cast<const float4*>(feats + (size_t)p * 256 + lane * 4);
    int np = npts_arr[p];
    int cx = coors[p * 4 + 3], cy = coors[p * 4 + 2];
    while (true) {
      const int p2 = p + nw;
      const bool has2 = p2 < P;
      float4 f2 = make_float4(0.f, 0.f, 0.f, 0.f);
      int np2 = 1, cx2 = 0, cy2 = 0;
      if (has2) {  // prefetch next pillar
        f2 = *reinterpret_cast<const float4*>(feats + (size_t)p2 * 256 +
                                              lane * 4);
        np2 = npts_arr[p2];
        cx2 = coors[p2 * 4 + 3];
        cy2 = coors[p2 * 4 + 2];
      }
      const float ox = (float)cx * VX_ + X_OFF_;
      const float oy = (float)cy * VY_ + Y_OFF_;
      const float inv = 1.f / (float)np;
      const float m0 = wave_sum(f.x) * inv;
      const float m1 = wave_sum(f.y) * inv;
      const float m2 = wave_sum(f.z) * inv;
      if (lane == 0) {  // per-pillar aux for k4 (fire-and-forget stores)
        *reinterpret_cast<float4*>(aux + (size_t)p * 8) =
            make_float4(m0, m1, m2, ox);
        *reinterpret_cast<float4*>(aux + (size_t)p * 8 + 4) =
            make_float4(oy, __int_as_float(np), 0.f, 0.f);
      }
      const bool valid = lane < np;
      float ft[9] = {f.x,      f.y,      f.z,      f.w,      f.x - m0,
                     f.y - m1, f.z - m2, f.x - ox, f.y - oy};
#pragma unroll
      for (int c = 0; c < 9; ++c) ft[c] = valid ? ft[c] : 0.f;
      int idx = 0;
      float t1 = 0.f, t2 = 0.f;
#pragma unroll
      for (int c = 0; c < 9; ++c) {
        float u = 0.f;
#pragma unroll
        for (int c2 = c; c2 < 9; ++c2) u = fmaf(g[idx++], ft[c2], u);
        t2 = fmaf(ft[c], u, t2);
        t1 = fmaf(ft[c], wsv[c], t1);
      }
      s1 += t1;
      s2 += t2;
      if (!has2) break;
      p = p2;
      f = f2;
      np = np2;
      cx = cx2;
      cy = cy2;
    }
  }
  red[wv][lane] = make_float2(s1, s2);
  __syncthreads();
  if (t < 64) {
    const float v = red[0][t].x + red[1][t].x + red[2][t].x + red[3][t].x;
    partials[((size_t)t * 2 + 0) * S + blockIdx.x] = v;
  } else if (t < 128) {
    const int n = t - 64;
    const float v = red[0][n].y + red[1][n].y + red[2][n].y + red[3][n].y;
    partials[((size_t)n * 2 + 1) * S + blockIdx.x] = v;
  }
}

// k2: reduce partials (coalesced), compute a[n], b[n]. One block per n.
__global__ __launch_bounds__(256) void k2_stats(
    const float* __restrict__ partials, const float* __restrict__ gamma,
    const float* __restrict__ beta, float* __restrict__ ab, int S, int P) {
  const int n = blockIdx.x, t = threadIdx.x;
  __shared__ float r1[4], r2[4];
  const float* p1 = partials + ((size_t)n * 2 + 0) * S;
  const float* p2 = partials + ((size_t)n * 2 + 1) * S;
  float a1 = 0.f, a2 = 0.f;
  for (int b = t; b < S; b += 256) {
    a1 += p1[b];
    a2 += p2[b];
  }
  a1 = wave_sum(a1);
  a2 = wave_sum(a2);
  const int wv = t >> 6;
  if ((t & 63) == 0) {
    r1[wv] = a1;
    r2[wv] = a2;
  }
  __syncthreads();
  if (t == 0) {
    const float v2 = r1[0] + r1[1] + r1[2] + r1[3];  // sum x
    const float v1 = r2[0] + r2[1] + r2[2] + r2[3];  // sum x^2
    const float invPN = 1.f / ((float)P * 64.f);
    const float mu = v2 * invPN;
    const float var = v1 * invPN - mu * mu;
    const float a = gamma[n] * rsqrtf(var + EPS_);
    const float b = beta[n] - mu * a;
    ab[n] = a;
    ab[64 + n] = b;
  }
}

// k4 (R14): A fragments built DIRECTLY from global per lane — no A_lds, no
// ds_write/ds_read round-trip. Lane (g16,l16), subtile mt covers row
// mt*16+l16, k-slice 8*g16..8*g16+7:
//   g16=0 -> ft[0..7] of the row; g16=1 -> {ft[8],0..}; g16>=2 -> zeros.
// Rows masked by row<np. aux gives wave-uniform m0,m1,m2,ox,oy,np.
__global__ __launch_bounds__(256) void k4_mfma(
    const float* __restrict__ feats, const float* __restrict__ aux,
    const uint32_t* __restrict__ Bpack, const float* __restrict__ ab,
    float* __restrict__ out, int P) {
  __shared__ float2 shab[64];
  const int t = threadIdx.x, lane = t & 63, wv = t >> 6;
  const int g16 = lane >> 4, l16 = lane & 15;
  if (t < 64) shab[t] = make_float2(ab[t], ab[64 + t]);

  uint4 bq[4];
#pragma unroll
  for (int nt = 0; nt < 4; ++nt)
    bq[nt] =
        *reinterpret_cast<const uint4*>(Bpack + ((size_t)nt * 64 + lane) * 4);
  __syncthreads();

  float ar[16], br[16];
#pragma unroll
  for (int i = 0; i < 16; ++i) {
    const int n = (i >> 2) * 16 + g16 * 4 + (i & 3);
    const float2 v = shab[n];
    ar[i] = v.x;
    br[i] = v.y;
  }

  const int stride = gridDim.x * 4;
  int p = blockIdx.x * 4 + wv;
  if (p >= P) return;

  float4 fr0, fr1, fr2, fr3, a0, a1;
  {
    const float* base = feats + (size_t)p * 256 + l16 * 4;
    fr0 = *reinterpret_cast<const float4*>(base);
    fr1 = *reinterpret_cast<const float4*>(base + 64);
    fr2 = *reinterpret_cast<const float4*>(base + 128);
    fr3 = *reinterpret_cast<const float4*>(base + 192);
    a0 = *reinterpret_cast<const float4*>(aux + (size_t)p * 8);
    a1 = *reinterpret_cast<const float4*>(aux + (size_t)p * 8 + 4);
  }
  while (true) {
    const int p2 = p + stride;
    const bool has2 = p2 < P;
    float4 fr0b, fr1b, fr2b, fr3b, a0b, a1b;
    if (has2) {  // prefetch next pillar (4 row-quads + aux)
      const float* base = feats + (size_t)p2 * 256 + l16 * 4;
      fr0b = *reinterpret_cast<const float4*>(base);
      fr1b = *reinterpret_cast<const float4*>(base + 64);
      fr2b = *reinterpret_cast<const float4*>(base + 128);
      fr3b = *reinterpret_cast<const float4*>(base + 192);
      a0b = *reinterpret_cast<const float4*>(aux + (size_t)p2 * 8);
      a1b = *reinterpret_cast<const float4*>(aux + (size_t)p2 * 8 + 4);
    }
    const float m0 = a0.x, m1 = a0.y, m2 = a0.z, ox = a0.w, oy = a1.x;
    const int np = __float_as_int(a1.y);

    bf16x8 afr[4];
    const float4 frs[4] = {fr0, fr1, fr2, fr3};
#pragma unroll
    for (int mt = 0; mt < 4; ++mt) {
      const float4 f = frs[mt];
      const bool valid = (mt * 16 + l16) < np;
      uint4 q;
      if (g16 == 0) {
        q.x = cvtpk(f.x, f.y);
        q.y = cvtpk(f.z, f.w);
        q.z = cvtpk(f.x - m0, f.y - m1);
        q.w = cvtpk(f.z - m2, f.x - ox);
      } else if (g16 == 1) {
        q.x = cvtpk(f.y - oy, 0.f);
        q.y = 0u;
        q.z = 0u;
        q.w = 0u;
      } else {
        q = make_uint4(0u, 0u, 0u, 0u);
      }
      if (!valid) q = make_uint4(0u, 0u, 0u, 0u);
      afr[mt] = __builtin_bit_cast(bf16x8, q);
    }

    const f32x4 accz = {0.f, 0.f, 0.f, 0.f};
    float mx[4] = {0.f, 0.f, 0.f, 0.f};  // init 0 == fused relu
#pragma unroll
    for (int mt = 0; mt < 4; ++mt) {
      const bf16x8 a = afr[mt];
#pragma unroll
      for (int nt = 0; nt < 4; ++nt) {
        f32x4 acc4 = __builtin_amdgcn_mfma_f32_16x16x32_bf16(
            a, __builtin_bit_cast(bf16x8, bq[nt]), accz, 0, 0, 0);
#pragma unroll
        for (int r = 0; r < 4; ++r) {
          const float y = fmaf(acc4[r], ar[mt * 4 + r], br[mt * 4 + r]);
          mx[nt] = fmaxf(mx[nt], y);
        }
      }
    }
#pragma unroll
    for (int nt = 0; nt < 4; ++nt) {
      mx[nt] = fmaxf(mx[nt], __shfl_xor(mx[nt], 16));
      mx[nt] = fmaxf(mx[nt], __shfl_xor(mx[nt], 32));
    }
    const float outv =
        (g16 == 0) ? mx[0] : (g16 == 1) ? mx[1] : (g16 == 2) ? mx[2] : mx[3];
    out[(size_t)p * 64 + lane] = outv;  // o = g16*16 + l16 == lane
    if (!has2) break;
    p = p2;
    fr0 = fr0b;
    fr1 = fr1b;
    fr2 = fr2b;
    fr3 = fr3b;
    a0 = a0b;
    a1 = a1b;
  }
}

extern "C" void kernel_launch(void* const* d_in, const int* in_sizes, int n_in,
                              void* d_out, int out_size, void* d_ws,
                              size_t ws_size, hipStream_t stream) {
  const float* feats = (const float*)d_in[0];
  const int* npts = (const int*)d_in[1];
  const int* coors = (const int*)d_in[2];
  const float* W = (const float*)d_in[3];
  const float* gamma = (const float*)d_in[4];
  const float* beta = (const float*)d_in[5];
  float* out = (float*)d_out;
  float* ws = (float*)d_ws;

  const int P = in_sizes[1];  // num_points has P elements

  float* gws = ws;                          // [64]  G' + wsum
  uint32_t* Bpack = (uint32_t*)(ws + 64);   // [1024] u32 = 4x64 uint4 frags
  float* ab = ws + 64 + 1024;               // [128]: a[64], b[64]
  float* aux = ws + 1216;                   // [8*P]: per-pillar aux
  float* partials = ws + 1216 + 8 * (size_t)P;  // [64][2][S]

  int S = 2048;
  while (S > 1 &&
         (size_t)(64 * 2 * (size_t)S + 1216 + 8 * (size_t)P) * 4 > ws_size)
    S >>= 1;

  k0_prep<<<1, 256, 0, stream>>>(W, gws, Bpack);
  k1_moments<<<S, 256, 0, stream>>>(feats, npts, coors, gws, partials, aux, S,
                                    P);
  k2_stats<<<64, 256, 0, stream>>>(partials, gamma, beta, ab, S, P);
  const int g8 = (P + 31) / 32;  // 4 waves/block, ~8 pillars/wave
  k4_mfma<<<g8, 256, 0, stream>>>(feats, aux, Bpack, ab, out, P);
}

// Round 16
// 42.868 us; speedup vs baseline: 1.1263x; 1.1263x over previous
//
#include <hip/hip_runtime.h>
#include <hip/hip_bf16.h>
#include <math.h>

typedef __attribute__((ext_vector_type(8))) __bf16 bf16x8;
typedef __attribute__((ext_vector_type(4))) float f32x4;

constexpr float VX_ = 0.2f;
constexpr float VY_ = 0.2f;
constexpr float X_OFF_ = 0.1f;    // VX/2 + 0.0
constexpr float Y_OFF_ = -39.9f;  // VY/2 - 40.0
constexpr float EPS_ = 1e-3f;

#define S1 512  // k1 block count; partials = [64][2][S1]

__device__ __forceinline__ float wave_sum(float v) {
#pragma unroll
  for (int off = 32; off; off >>= 1) v += __shfl_xor(v, off);
  return v;
}

__device__ __forceinline__ ushort bf16bits(float x) {
  __hip_bfloat16 h = __float2bfloat16(x);
  return __builtin_bit_cast(ushort, h);
}

// packed RNE f32x2 -> bf16x2 (gfx950 has the instruction but no builtin)
__device__ __forceinline__ uint32_t cvtpk(float lo, float hi) {
  uint32_t r;
  asm("v_cvt_pk_bf16_f32 %0, %1, %2" : "=v"(r) : "v"(lo), "v"(hi));
  return r;
}

// k1: inline concurrent prep (W->LDS, G' = scaled W^T W + wsum, proven R9)
// + per-n moments pre-contracted to 2 floats/thread + per-pillar aux
// {m0,m1,m2,ox,oy,np} (proven R12). Non-atomic partials, layout
// [(n*2+j)*S1 + block]. Block 0 also packs the MFMA B fragments (k0 code).
__global__ __launch_bounds__(256) void k1_moments(
    const float* __restrict__ feats, const int* __restrict__ npts_arr,
    const int* __restrict__ coors, const float* __restrict__ W,
    float* __restrict__ partials, float* __restrict__ aux,
    uint32_t* __restrict__ Bpack, int P) {
  __shared__ float W_lds[576];
  __shared__ float gws[54];  // G'[45] (off-diag doubled) + wsum[9]
  __shared__ float2 red[4][64];
  const int t = threadIdx.x, lane = t & 63, wv = t >> 6;

  for (int i = t; i < 576; i += 256) W_lds[i] = W[i];
  __syncthreads();
  if (t < 180) {  // G': 45 pairs x 4-way split over o
    const int pr = t >> 2, k = t & 3;
    int c = 0, rem = pr;
    while (rem >= 9 - c) {
      rem -= 9 - c;
      ++c;
    }
    const int c2 = c + rem;
    float s = 0.f;
    for (int o = k * 16; o < k * 16 + 16; ++o)
      s += W_lds[o * 9 + c] * W_lds[o * 9 + c2];
    s += __shfl_xor(s, 1);
    s += __shfl_xor(s, 2);
    if (k == 0) gws[pr] = (c == c2) ? s : 2.f * s;
  } else if (t < 216) {  // wsum: 9 cols x 4-way split
    const int tt = t - 180, c = tt >> 2, k = tt & 3;
    float s = 0.f;
    for (int o = k * 16; o < k * 16 + 16; ++o) s += W_lds[o * 9 + c];
    s += __shfl_xor(s, 1);
    s += __shfl_xor(s, 2);
    if (k == 0) gws[45 + c] = s;
  }
  __syncthreads();
  float g[45], wsv[9];
#pragma unroll
  for (int i = 0; i < 45; ++i) g[i] = gws[i];
#pragma unroll
  for (int i = 0; i < 9; ++i) wsv[i] = gws[45 + i];

  if (blockIdx.x == 0) {  // Bpack build (k0 verbatim, from W_lds)
    const int nt = t >> 6, bl = t & 63;
    const int l16 = bl & 15, g16 = bl >> 4;
    const int col = nt * 16 + l16;
    ushort h[8];
#pragma unroll
    for (int j = 0; j < 8; ++j) {
      const int kk = 8 * g16 + j;
      h[j] = (kk < 9) ? bf16bits(W_lds[col * 9 + kk]) : (ushort)0;
    }
    uint4 q;
    q.x = (uint)h[0] | ((uint)h[1] << 16);
    q.y = (uint)h[2] | ((uint)h[3] << 16);
    q.z = (uint)h[4] | ((uint)h[5] << 16);
    q.w = (uint)h[6] | ((uint)h[7] << 16);
    *reinterpret_cast<uint4*>(Bpack + (size_t)t * 4) = q;
  }

  float s1 = 0.f, s2 = 0.f;
  const int nw = S1 * 4;
  int p = blockIdx.x * 4 + wv;
  if (p < P) {
    float4 f =
        *reinterpret_cast<const float4*>(feats + (size_t)p * 256 + lane * 4);
    int np = npts_arr[p];
    int cx = coors[p * 4 + 3], cy = coors[p * 4 + 2];
    while (true) {
      const int p2 = p + nw;
      const bool has2 = p2 < P;
      float4 f2 = make_float4(0.f, 0.f, 0.f, 0.f);
      int np2 = 1, cx2 = 0, cy2 = 0;
      if (has2) {  // prefetch next pillar
        f2 = *reinterpret_cast<const float4*>(feats + (size_t)p2 * 256 +
                                              lane * 4);
        np2 = npts_arr[p2];
        cx2 = coors[p2 * 4 + 3];
        cy2 = coors[p2 * 4 + 2];
      }
      const float ox = (float)cx * VX_ + X_OFF_;
      const float oy = (float)cy * VY_ + Y_OFF_;
      const float inv = 1.f / (float)np;
      const float m0 = wave_sum(f.x) * inv;
      const float m1 = wave_sum(f.y) * inv;
      const float m2 = wave_sum(f.z) * inv;
      if (lane == 0) {  // per-pillar aux for k4 (fire-and-forget stores)
        *reinterpret_cast<float4*>(aux + (size_t)p * 8) =
            make_float4(m0, m1, m2, ox);
        *reinterpret_cast<float4*>(aux + (size_t)p * 8 + 4) =
            make_float4(oy, __int_as_float(np), 0.f, 0.f);
      }
      const bool valid = lane < np;
      float ft[9] = {f.x,      f.y,      f.z,      f.w,      f.x - m0,
                     f.y - m1, f.z - m2, f.x - ox, f.y - oy};
#pragma unroll
      for (int c = 0; c < 9; ++c) ft[c] = valid ? ft[c] : 0.f;
      int idx = 0;
      float t1 = 0.f, t2 = 0.f;
#pragma unroll
      for (int c = 0; c < 9; ++c) {
        float u = 0.f;
#pragma unroll
        for (int c2 = c; c2 < 9; ++c2) u = fmaf(g[idx++], ft[c2], u);
        t2 = fmaf(ft[c], u, t2);
        t1 = fmaf(ft[c], wsv[c], t1);
      }
      s1 += t1;
      s2 += t2;
      if (!has2) break;
      p = p2;
      f = f2;
      np = np2;
      cx = cx2;
      cy = cy2;
    }
  }
  red[wv][lane] = make_float2(s1, s2);
  __syncthreads();
  if (t < 64) {
    const float v = red[0][t].x + red[1][t].x + red[2][t].x + red[3][t].x;
    partials[((size_t)t * 2 + 0) * S1 + blockIdx.x] = v;
  } else if (t < 128) {
    const int n = t - 64;
    const float v = red[0][n].y + red[1][n].y + red[2][n].y + red[3][n].y;
    partials[((size_t)n * 2 + 1) * S1 + blockIdx.x] = v;
  }
}

// k2: reduce partials (coalesced), compute a[n], b[n]. One block per n.
__global__ __launch_bounds__(256) void k2_stats(
    const float* __restrict__ partials, const float* __restrict__ gamma,
    const float* __restrict__ beta, float* __restrict__ ab, int P) {
  const int n = blockIdx.x, t = threadIdx.x;
  __shared__ float r1[4], r2[4];
  const float* p1 = partials + ((size_t)n * 2 + 0) * S1;
  const float* p2 = partials + ((size_t)n * 2 + 1) * S1;
  float a1 = 0.f, a2 = 0.f;
  for (int b = t; b < S1; b += 256) {
    a1 += p1[b];
    a2 += p2[b];
  }
  a1 = wave_sum(a1);
  a2 = wave_sum(a2);
  const int wv = t >> 6;
  if ((t & 63) == 0) {
    r1[wv] = a1;
    r2[wv] = a2;
  }
  __syncthreads();
  if (t == 0) {
    const float v2 = r1[0] + r1[1] + r1[2] + r1[3];  // sum x
    const float v1 = r2[0] + r2[1] + r2[2] + r2[3];  // sum x^2
    const float invPN = 1.f / ((float)P * 64.f);
    const float mu = v2 * invPN;
    const float var = v1 * invPN - mu * mu;
    const float a = gamma[n] * rsqrtf(var + EPS_);
    const float b = beta[n] - mu * a;
    ab[n] = a;
    ab[64 + n] = b;
  }
}

// k4 (R16): R12's proven MFMA body, ONE pillar per wave (no loop) — grid
// ceil(P/4) blocks x 4 waves. Short-lived blocks stream through the CU so
// the per-pillar dependency chain overlaps across blocks, not within a wave.
__global__ __launch_bounds__(256) void k4_mfma(
    const float* __restrict__ feats, const float* __restrict__ aux,
    const uint32_t* __restrict__ Bpack, const float* __restrict__ ab,
    float* __restrict__ out, int P) {
  __shared__ uint32_t A_lds[4][64][20];  // rows padded to 80 B
  __shared__ float2 shab[64];
  const int t = threadIdx.x, lane = t & 63, wv = t >> 6;
  const int g16 = lane >> 4, l16 = lane & 15;
  if (t < 64) shab[t] = make_float2(ab[t], ab[64 + t]);

  uint4 bq[4];
#pragma unroll
  for (int nt = 0; nt < 4; ++nt)
    bq[nt] =
        *reinterpret_cast<const uint4*>(Bpack + ((size_t)nt * 64 + lane) * 4);

  // zero the permanently-zero k-slots 6..15 of this wave's rows
  A_lds[wv][lane][6] = 0u;
  A_lds[wv][lane][7] = 0u;
  *reinterpret_cast<uint4*>(&A_lds[wv][lane][8]) = make_uint4(0u, 0u, 0u, 0u);
  *reinterpret_cast<uint4*>(&A_lds[wv][lane][12]) = make_uint4(0u, 0u, 0u, 0u);
  __syncthreads();

  float ar[16], br[16];
#pragma unroll
  for (int i = 0; i < 16; ++i) {
    const int n = (i >> 2) * 16 + g16 * 4 + (i & 3);
    const float2 v = shab[n];
    ar[i] = v.x;
    br[i] = v.y;
  }

  const int p = blockIdx.x * 4 + wv;
  if (p >= P) return;
  const float4 f =
      *reinterpret_cast<const float4*>(feats + (size_t)p * 256 + lane * 4);
  const float4 a0 = *reinterpret_cast<const float4*>(aux + (size_t)p * 8);
  const float4 a1 = *reinterpret_cast<const float4*>(aux + (size_t)p * 8 + 4);

  const float m0 = a0.x, m1 = a0.y, m2 = a0.z, ox = a0.w, oy = a1.x;
  const int np = __float_as_int(a1.y);
  const bool valid = lane < np;
  const float v0 = valid ? f.x : 0.f;
  const float v1 = valid ? f.y : 0.f;
  const float v2 = valid ? f.z : 0.f;
  const float v3 = valid ? f.w : 0.f;
  const float v4 = valid ? f.x - m0 : 0.f;
  const float v5 = valid ? f.y - m1 : 0.f;
  const float v6 = valid ? f.z - m2 : 0.f;
  const float v7 = valid ? f.x - ox : 0.f;
  const float v8 = valid ? f.y - oy : 0.f;
  union {
    uint32_t u[6];
    uint4 q;
  } pk;
  pk.u[0] = cvtpk(v0, v1);
  pk.u[1] = cvtpk(v2, v3);
  pk.u[2] = cvtpk(v4, v5);
  pk.u[3] = cvtpk(v6, v7);
  pk.u[4] = cvtpk(v8, 0.f);
  // stage this lane's A row (lane == n); same-wave ds_write->ds_read is
  // in-order and each wave owns its A_lds[wv] region: no barrier needed.
  *reinterpret_cast<uint4*>(&A_lds[wv][lane][0]) = pk.q;
  *reinterpret_cast<uint2*>(&A_lds[wv][lane][4]) = make_uint2(pk.u[4], 0u);

  bf16x8 afr[4];
#pragma unroll
  for (int mt = 0; mt < 4; ++mt) {
    afr[mt] =
        *reinterpret_cast<const bf16x8*>(&A_lds[wv][mt * 16 + l16][g16 * 4]);
  }
  const f32x4 accz = {0.f, 0.f, 0.f, 0.f};
  float mx[4] = {0.f, 0.f, 0.f, 0.f};  // init 0 == fused relu
#pragma unroll
  for (int mt = 0; mt < 4; ++mt) {
    const bf16x8 a = afr[mt];
#pragma unroll
    for (int nt = 0; nt < 4; ++nt) {
      f32x4 acc4 = __builtin_amdgcn_mfma_f32_16x16x32_bf16(
          a, __builtin_bit_cast(bf16x8, bq[nt]), accz, 0, 0, 0);
#pragma unroll
      for (int r = 0; r < 4; ++r) {
        const float y = fmaf(acc4[r], ar[mt * 4 + r], br[mt * 4 + r]);
        mx[nt] = fmaxf(mx[nt], y);
      }
    }
  }
#pragma unroll
  for (int nt = 0; nt < 4; ++nt) {
    mx[nt] = fmaxf(mx[nt], __shfl_xor(mx[nt], 16));
    mx[nt] = fmaxf(mx[nt], __shfl_xor(mx[nt], 32));
  }
  const float outv =
      (g16 == 0) ? mx[0] : (g16 == 1) ? mx[1] : (g16 == 2) ? mx[2] : mx[3];
  out[(size_t)p * 64 + lane] = outv;  // o = g16*16 + l16 == lane
}

extern "C" void kernel_launch(void* const* d_in, const int* in_sizes, int n_in,
                              void* d_out, int out_size, void* d_ws,
                              size_t ws_size, hipStream_t stream) {
  const float* feats = (const float*)d_in[0];
  const int* npts = (const int*)d_in[1];
  const int* coors = (const int*)d_in[2];
  const float* W = (const float*)d_in[3];
  const float* gamma = (const float*)d_in[4];
  const float* beta = (const float*)d_in[5];
  float* out = (float*)d_out;
  float* ws = (float*)d_ws;

  const int P = in_sizes[1];  // num_points has P elements

  float* ab = ws;                              // [128]: a[64], b[64]
  uint32_t* Bpack = (uint32_t*)(ws + 128);     // [1024] u32 = 4x64 frags
  float* partials = ws + 128 + 1024;           // [64][2][S1]
  float* aux = partials + 64 * 2 * S1;         // [8*P]

  k1_moments<<<S1, 256, 0, stream>>>(feats, npts, coors, W, partials, aux,
                                     Bpack, P);
  k2_stats<<<64, 256, 0, stream>>>(partials, gamma, beta, ab, P);
  const int g1 = (P + 3) / 4;  // 4 waves/block, 1 pillar/wave
  k4_mfma<<<g1, 256, 0, stream>>>(feats, aux, Bpack, ab, out, P);
}

// Round 17
// 39.752 us; speedup vs baseline: 1.2146x; 1.0784x over previous
//
#include <hip/hip_runtime.h>
#include <hip/hip_bf16.h>
#include <math.h>

typedef __attribute__((ext_vector_type(8))) __bf16 bf16x8;
typedef __attribute__((ext_vector_type(4))) float f32x4;

constexpr float VX_ = 0.2f;
constexpr float VY_ = 0.2f;
constexpr float X_OFF_ = 0.1f;    // VX/2 + 0.0
constexpr float Y_OFF_ = -39.9f;  // VY/2 - 40.0
constexpr float EPS_ = 1e-3f;

#define S1 512  // k1 block count; partials = [64][2][S1]

__device__ __forceinline__ float wave_sum(float v) {
#pragma unroll
  for (int off = 32; off; off >>= 1) v += __shfl_xor(v, off);
  return v;
}

__device__ __forceinline__ ushort bf16bits(float x) {
  __hip_bfloat16 h = __float2bfloat16(x);
  return __builtin_bit_cast(ushort, h);
}

// packed RNE f32x2 -> bf16x2 (gfx950 has the instruction but no builtin)
__device__ __forceinline__ uint32_t cvtpk(float lo, float hi) {
  uint32_t r;
  asm("v_cvt_pk_bf16_f32 %0, %1, %2" : "=v"(r) : "v"(lo), "v"(hi));
  return r;
}

// k1: inline concurrent prep (W->LDS, G' = scaled W^T W + wsum) + per-n
// moments pre-contracted to 2 floats/thread + per-pillar aux
// {m0,m1,m2,ox,oy,np}. Non-atomic partials [(n*2+j)*S1 + block].
// Block 0 also packs the MFMA B fragments, with B[9][o] = 1.0 (bias
// channel for the fused BN affine in k4).
__global__ __launch_bounds__(256) void k1_moments(
    const float* __restrict__ feats, const int* __restrict__ npts_arr,
    const int* __restrict__ coors, const float* __restrict__ W,
    float* __restrict__ partials, float* __restrict__ aux,
    uint32_t* __restrict__ Bpack, int P) {
  __shared__ float W_lds[576];
  __shared__ float gws[54];  // G'[45] (off-diag doubled) + wsum[9]
  __shared__ float2 red[4][64];
  const int t = threadIdx.x, lane = t & 63, wv = t >> 6;

  for (int i = t; i < 576; i += 256) W_lds[i] = W[i];
  __syncthreads();
  if (t < 180) {  // G': 45 pairs x 4-way split over o
    const int pr = t >> 2, k = t & 3;
    int c = 0, rem = pr;
    while (rem >= 9 - c) {
      rem -= 9 - c;
      ++c;
    }
    const int c2 = c + rem;
    float s = 0.f;
    for (int o = k * 16; o < k * 16 + 16; ++o)
      s += W_lds[o * 9 + c] * W_lds[o * 9 + c2];
    s += __shfl_xor(s, 1);
    s += __shfl_xor(s, 2);
    if (k == 0) gws[pr] = (c == c2) ? s : 2.f * s;
  } else if (t < 216) {  // wsum: 9 cols x 4-way split
    const int tt = t - 180, c = tt >> 2, k = tt & 3;
    float s = 0.f;
    for (int o = k * 16; o < k * 16 + 16; ++o) s += W_lds[o * 9 + c];
    s += __shfl_xor(s, 1);
    s += __shfl_xor(s, 2);
    if (k == 0) gws[45 + c] = s;
  }
  __syncthreads();
  float g[45], wsv[9];
#pragma unroll
  for (int i = 0; i < 45; ++i) g[i] = gws[i];
#pragma unroll
  for (int i = 0; i < 9; ++i) wsv[i] = gws[45 + i];

  if (blockIdx.x == 0) {  // Bpack build; kk==9 -> 1.0 (bias channel)
    const int nt = t >> 6, bl = t & 63;
    const int l16 = bl & 15, g16 = bl >> 4;
    const int col = nt * 16 + l16;
    ushort h[8];
#pragma unroll
    for (int j = 0; j < 8; ++j) {
      const int kk = 8 * g16 + j;
      h[j] = (kk < 9) ? bf16bits(W_lds[col * 9 + kk])
                      : ((kk == 9) ? bf16bits(1.0f) : (ushort)0);
    }
    uint4 q;
    q.x = (uint)h[0] | ((uint)h[1] << 16);
    q.y = (uint)h[2] | ((uint)h[3] << 16);
    q.z = (uint)h[4] | ((uint)h[5] << 16);
    q.w = (uint)h[6] | ((uint)h[7] << 16);
    *reinterpret_cast<uint4*>(Bpack + (size_t)t * 4) = q;
  }

  float s1 = 0.f, s2 = 0.f;
  const int nw = S1 * 4;
  int p = blockIdx.x * 4 + wv;
  if (p < P) {
    float4 f =
        *reinterpret_cast<const float4*>(feats + (size_t)p * 256 + lane * 4);
    int np = npts_arr[p];
    int cx = coors[p * 4 + 3], cy = coors[p * 4 + 2];
    while (true) {
      const int p2 = p + nw;
      const bool has2 = p2 < P;
      float4 f2 = make_float4(0.f, 0.f, 0.f, 0.f);
      int np2 = 1, cx2 = 0, cy2 = 0;
      if (has2) {  // prefetch next pillar
        f2 = *reinterpret_cast<const float4*>(feats + (size_t)p2 * 256 +
                                              lane * 4);
        np2 = npts_arr[p2];
        cx2 = coors[p2 * 4 + 3];
        cy2 = coors[p2 * 4 + 2];
      }
      const float ox = (float)cx * VX_ + X_OFF_;
      const float oy = (float)cy * VY_ + Y_OFF_;
      const float inv = 1.f / (float)np;
      const float m0 = wave_sum(f.x) * inv;
      const float m1 = wave_sum(f.y) * inv;
      const float m2 = wave_sum(f.z) * inv;
      if (lane == 0) {  // per-pillar aux for k4 (fire-and-forget stores)
        *reinterpret_cast<float4*>(aux + (size_t)p * 8) =
            make_float4(m0, m1, m2, ox);
        *reinterpret_cast<float4*>(aux + (size_t)p * 8 + 4) =
            make_float4(oy, __int_as_float(np), 0.f, 0.f);
      }
      const bool valid = lane < np;
      float ft[9] = {f.x,      f.y,      f.z,      f.w,      f.x - m0,
                     f.y - m1, f.z - m2, f.x - ox, f.y - oy};
#pragma unroll
      for (int c = 0; c < 9; ++c) ft[c] = valid ? ft[c] : 0.f;
      int idx = 0;
      float t1 = 0.f, t2 = 0.f;
#pragma unroll
      for (int c = 0; c < 9; ++c) {
        float u = 0.f;
#pragma unroll
        for (int c2 = c; c2 < 9; ++c2) u = fmaf(g[idx++], ft[c2], u);
        t2 = fmaf(ft[c], u, t2);
        t1 = fmaf(ft[c], wsv[c], t1);
      }
      s1 += t1;
      s2 += t2;
      if (!has2) break;
      p = p2;
      f = f2;
      np = np2;
      cx = cx2;
      cy = cy2;
    }
  }
  red[wv][lane] = make_float2(s1, s2);
  __syncthreads();
  if (t < 64) {
    const float v = red[0][t].x + red[1][t].x + red[2][t].x + red[3][t].x;
    partials[((size_t)t * 2 + 0) * S1 + blockIdx.x] = v;
  } else if (t < 128) {
    const int n = t - 64;
    const float v = red[0][n].y + red[1][n].y + red[2][n].y + red[3][n].y;
    partials[((size_t)n * 2 + 1) * S1 + blockIdx.x] = v;
  }
}

// k2: reduce partials (coalesced), compute a[n], b[n]. One block per n.
__global__ __launch_bounds__(256) void k2_stats(
    const float* __restrict__ partials, const float* __restrict__ gamma,
    const float* __restrict__ beta, float* __restrict__ ab, int P) {
  const int n = blockIdx.x, t = threadIdx.x;
  __shared__ float r1[4], r2[4];
  const float* p1 = partials + ((size_t)n * 2 + 0) * S1;
  const float* p2 = partials + ((size_t)n * 2 + 1) * S1;
  float a1 = 0.f, a2 = 0.f;
  for (int b = t; b < S1; b += 256) {
    a1 += p1[b];
    a2 += p2[b];
  }
  a1 = wave_sum(a1);
  a2 = wave_sum(a2);
  const int wv = t >> 6;
  if ((t & 63) == 0) {
    r1[wv] = a1;
    r2[wv] = a2;
  }
  __syncthreads();
  if (t == 0) {
    const float v2 = r1[0] + r1[1] + r1[2] + r1[3];  // sum x
    const float v1 = r2[0] + r2[1] + r2[2] + r2[3];  // sum x^2
    const float invPN = 1.f / ((float)P * 64.f);
    const float mu = v2 * invPN;
    const float var = v1 * invPN - mu * mu;
    const float a = gamma[n] * rsqrtf(var + EPS_);
    const float b = beta[n] - mu * a;
    ab[n] = a;
    ab[64 + n] = b;
  }
}

// k4 (R17): BN affine folded INTO the MFMA. Lane packs its OWN row n=lane:
// A[n][k] = a_n * ft[k] (k<9, masked), A[n][9] = b_n; B[9][o] = 1.0. So
// acc4[r] == y = a_n*x + b_n directly — epilogue is a pure fmax tree, no
// ar/br registers, no shab LDS, no block barrier (A_lds is per-wave-owned).
// Invalid rows give y = b_n, matching the reference's x=0 rows.
__global__ __launch_bounds__(256) void k4_mfma(
    const float* __restrict__ feats, const float* __restrict__ aux,
    const uint32_t* __restrict__ Bpack, const float* __restrict__ ab,
    float* __restrict__ out, int P) {
  __shared__ uint32_t A_lds[4][64][20];  // rows padded to 80 B
  const int t = threadIdx.x, lane = t & 63, wv = t >> 6;
  const int g16 = lane >> 4, l16 = lane & 15;

  uint4 bq[4];
#pragma unroll
  for (int nt = 0; nt < 4; ++nt)
    bq[nt] =
        *reinterpret_cast<const uint4*>(Bpack + ((size_t)nt * 64 + lane) * 4);
  const float a_l = ab[lane];       // BN scale for this lane's row n==lane
  const float b_l = ab[64 + lane];  // BN bias

  // zero the permanently-zero k-slots 5..15 of this wave's rows
  A_lds[wv][lane][5] = 0u;
  A_lds[wv][lane][6] = 0u;
  A_lds[wv][lane][7] = 0u;
  *reinterpret_cast<uint4*>(&A_lds[wv][lane][8]) = make_uint4(0u, 0u, 0u, 0u);
  *reinterpret_cast<uint4*>(&A_lds[wv][lane][12]) = make_uint4(0u, 0u, 0u, 0u);
  // no __syncthreads: each wave exclusively owns A_lds[wv]

  const int p = blockIdx.x * 4 + wv;
  if (p >= P) return;
  const float4 f =
      *reinterpret_cast<const float4*>(feats + (size_t)p * 256 + lane * 4);
  const float4 a0 = *reinterpret_cast<const float4*>(aux + (size_t)p * 8);
  const float4 a1 = *reinterpret_cast<const float4*>(aux + (size_t)p * 8 + 4);

  const float m0 = a0.x, m1 = a0.y, m2 = a0.z, ox = a0.w, oy = a1.x;
  const int np = __float_as_int(a1.y);
  const bool valid = lane < np;
  const float v0 = valid ? a_l * f.x : 0.f;
  const float v1 = valid ? a_l * f.y : 0.f;
  const float v2 = valid ? a_l * f.z : 0.f;
  const float v3 = valid ? a_l * f.w : 0.f;
  const float v4 = valid ? a_l * (f.x - m0) : 0.f;
  const float v5 = valid ? a_l * (f.y - m1) : 0.f;
  const float v6 = valid ? a_l * (f.z - m2) : 0.f;
  const float v7 = valid ? a_l * (f.x - ox) : 0.f;
  const float v8 = valid ? a_l * (f.y - oy) : 0.f;
  union {
    uint32_t u[6];
    uint4 q;
  } pk;
  pk.u[0] = cvtpk(v0, v1);
  pk.u[1] = cvtpk(v2, v3);
  pk.u[2] = cvtpk(v4, v5);
  pk.u[3] = cvtpk(v6, v7);
  pk.u[4] = cvtpk(v8, b_l);  // slot 9 = bias channel (always, even masked)
  // stage this lane's A row (lane == n); same-wave ds_write->ds_read is
  // in-order and each wave owns its A_lds[wv] region: no barrier needed.
  *reinterpret_cast<uint4*>(&A_lds[wv][lane][0]) = pk.q;
  A_lds[wv][lane][4] = pk.u[4];

  bf16x8 afr[4];
#pragma unroll
  for (int mt = 0; mt < 4; ++mt) {
    afr[mt] =
        *reinterpret_cast<const bf16x8*>(&A_lds[wv][mt * 16 + l16][g16 * 4]);
  }
  const f32x4 accz = {0.f, 0.f, 0.f, 0.f};
  float mx[4] = {0.f, 0.f, 0.f, 0.f};  // init 0 == fused relu
#pragma unroll
  for (int mt = 0; mt < 4; ++mt) {
    const bf16x8 a = afr[mt];
#pragma unroll
    for (int nt = 0; nt < 4; ++nt) {
      f32x4 acc4 = __builtin_amdgcn_mfma_f32_16x16x32_bf16(
          a, __builtin_bit_cast(bf16x8, bq[nt]), accz, 0, 0, 0);
#pragma unroll
      for (int r = 0; r < 4; ++r) mx[nt] = fmaxf(mx[nt], acc4[r]);
    }
  }
#pragma unroll
  for (int nt = 0; nt < 4; ++nt) {
    mx[nt] = fmaxf(mx[nt], __shfl_xor(mx[nt], 16));
    mx[nt] = fmaxf(mx[nt], __shfl_xor(mx[nt], 32));
  }
  const float outv =
      (g16 == 0) ? mx[0] : (g16 == 1) ? mx[1] : (g16 == 2) ? mx[2] : mx[3];
  out[(size_t)p * 64 + lane] = outv;  // o = g16*16 + l16 == lane
}

extern "C" void kernel_launch(void* const* d_in, const int* in_sizes, int n_in,
                              void* d_out, int out_size, void* d_ws,
                              size_t ws_size, hipStream_t stream) {
  const float* feats = (const float*)d_in[0];
  const int* npts = (const int*)d_in[1];
  const int* coors = (const int*)d_in[2];
  const float* W = (const float*)d_in[3];
  const float* gamma = (const float*)d_in[4];
  const float* beta = (const float*)d_in[5];
  float* out = (float*)d_out;
  float* ws = (float*)d_ws;

  const int P = in_sizes[1];  // num_points has P elements

  float* ab = ws;                              // [128]: a[64], b[64]
  uint32_t* Bpack = (uint32_t*)(ws + 128);     // [1024] u32 = 4x64 frags
  float* partials = ws + 128 + 1024;           // [64][2][S1]
  float* aux = partials + 64 * 2 * S1;         // [8*P]

  k1_moments<<<S1, 256, 0, stream>>>(feats, npts, coors, W, partials, aux,
                                     Bpack, P);
  k2_stats<<<64, 256, 0, stream>>>(partials, gamma, beta, ab, P);
  const int g1 = (P + 3) / 4;  // 4 waves/block, 1 pillar/wave
  k4_mfma<<<g1, 256, 0, stream>>>(feats, aux, Bpack, ab, out, P);
}